// Round 1
// baseline (5109.100 us; speedup 1.0000x reference)
//
#include <hip/hip_runtime.h>
#include <math.h>

#define N_NODES 1024
#define K_NB    32
#define H_DIM   256
#define DE_DIM  128
#define N_EXP   8
#define NTOPK   2
#define FFH     512

#define NH_ALL_F (N_EXP * N_NODES * H_DIM)  // 2097152 floats

// ---------------------------------------------------------------- helpers
__device__ __forceinline__ float gelu_f(float x) {
  // jax.nn.gelu default approximate=True (tanh form)
  float u = 0.7978845608028654f * (x + 0.044715f * x * x * x);
  float ex = __expf(2.f * u);
  float th = 1.f - 2.f / (ex + 1.f);   // tanh(u), inf-safe
  return 0.5f * x * (1.f + th);
}

// acc[r][j] += sum_i Xl[(r0+r)*XS + i] * W[i*LDW + c0 + j]
template<int CIN, int LDW, int XS>
__device__ __forceinline__ void mm_tile(float acc[8][4], const float* Xl, int r0,
                                        const float* __restrict__ W, int c0) {
#pragma unroll 2
  for (int i = 0; i < CIN; i += 4) {
    float4 w0 = *(const float4*)&W[(size_t)(i + 0) * LDW + c0];
    float4 w1 = *(const float4*)&W[(size_t)(i + 1) * LDW + c0];
    float4 w2 = *(const float4*)&W[(size_t)(i + 2) * LDW + c0];
    float4 w3 = *(const float4*)&W[(size_t)(i + 3) * LDW + c0];
#pragma unroll
    for (int r = 0; r < 8; ++r) {
      float4 xv = *(const float4*)&Xl[(r0 + r) * XS + i];
      acc[r][0] += xv.x * w0.x + xv.y * w1.x + xv.z * w2.x + xv.w * w3.x;
      acc[r][1] += xv.x * w0.y + xv.y * w1.y + xv.z * w2.y + xv.w * w3.y;
      acc[r][2] += xv.x * w0.z + xv.y * w1.z + xv.z * w2.z + xv.w * w3.z;
      acc[r][3] += xv.x * w0.w + xv.y * w1.w + xv.z * w2.w + xv.w * w3.w;
    }
  }
}

// X stored transposed+padded: x[r][i] = Xl[i*33 + r]
template<int CIN, int LDW>
__device__ __forceinline__ void mm_tile_t(float acc[8][4], const float* Xl, int r0,
                                          const float* __restrict__ W, int c0) {
#pragma unroll 2
  for (int i = 0; i < CIN; ++i) {
    float4 w = *(const float4*)&W[(size_t)i * LDW + c0];
#pragma unroll
    for (int r = 0; r < 8; ++r) {
      float xv = Xl[i * 33 + r0 + r];
      acc[r][0] += xv * w.x; acc[r][1] += xv * w.y;
      acc[r][2] += xv * w.z; acc[r][3] += xv * w.w;
    }
  }
}

// ---------------------------------------------------------------- gating
__global__ __launch_bounds__(64)
void gate_kernel(const float* __restrict__ nf, const float* __restrict__ wg,
                 int* __restrict__ sel_ne, float* __restrict__ sel_g) {
  int n = blockIdx.x, t = threadIdx.x;
  float p[8] = {0, 0, 0, 0, 0, 0, 0, 0};
  for (int j = 0; j < 4; ++j) {
    float x = nf[n * H_DIM + t + 64 * j];
#pragma unroll
    for (int e = 0; e < 8; ++e) p[e] += x * wg[(t + 64 * j) * 8 + e];
  }
#pragma unroll
  for (int e = 0; e < 8; ++e)
    for (int m = 32; m >= 1; m >>= 1) p[e] += __shfl_xor(p[e], m, 64);
  if (t == 0) {
    int i0 = 0; float v0 = p[0];
    for (int e = 1; e < 8; ++e) if (p[e] > v0) { v0 = p[e]; i0 = e; }
    int i1 = -1; float v1 = -3.4e38f;
    for (int e = 0; e < 8; ++e) if (e != i0 && p[e] > v1) { v1 = p[e]; i1 = e; }
    float g1 = __expf(v1 - v0);
    float inv = 1.f / (1.f + g1);
    sel_ne[n * 2 + 0] = (n << 3) | i0; sel_g[n * 2 + 0] = inv;
    sel_ne[n * 2 + 1] = (n << 3) | i1; sel_g[n * 2 + 1] = g1 * inv;
  }
}

__global__ __launch_bounds__(256)
void sort_kernel(const int* __restrict__ sel_ne, const float* __restrict__ sel_g,
                 int* __restrict__ work_ne, float* __restrict__ work_g) {
  __shared__ int cnt[8], off[8], cur[8];
  int t = threadIdx.x;
  if (t < 8) { cnt[t] = 0; cur[t] = 0; }
  __syncthreads();
  for (int i = t; i < N_NODES * NTOPK; i += 256) atomicAdd(&cnt[sel_ne[i] & 7], 1);
  __syncthreads();
  if (t == 0) { int s = 0; for (int e = 0; e < 8; ++e) { off[e] = s; s += cnt[e]; } }
  __syncthreads();
  for (int i = t; i < N_NODES * NTOPK; i += 256) {
    int pe = sel_ne[i]; int e = pe & 7;
    int pos = off[e] + atomicAdd(&cur[e], 1);
    work_ne[pos] = pe; work_g[pos] = sel_g[i];
  }
}

// per-expert LayerNorm of all nodes (ln_attn params)
__global__ __launch_bounds__(256)
void nh_kernel(const float* __restrict__ nf, const float* __restrict__ lag,
               const float* __restrict__ lab, float* __restrict__ nh_all) {
  __shared__ float red[8];
  int n = blockIdx.x, e = blockIdx.y, t = threadIdx.x;
  float x = nf[n * H_DIM + t];
  float sv = x, sq = x * x;
  for (int m = 32; m >= 1; m >>= 1) { sv += __shfl_xor(sv, m, 64); sq += __shfl_xor(sq, m, 64); }
  if ((t & 63) == 0) { red[t >> 6] = sv; red[4 + (t >> 6)] = sq; }
  __syncthreads();
  float sum = red[0] + red[1] + red[2] + red[3];
  float ssum = red[4] + red[5] + red[6] + red[7];
  float mu = sum * (1.f / 256.f);
  float var = ssum * (1.f / 256.f) - mu * mu;
  float rstd = rsqrtf(var + 1e-5f);
  nh_all[((size_t)e * N_NODES + n) * H_DIM + t] =
      (x - mu) * rstd * lag[e * H_DIM + t] + lab[e * H_DIM + t];
}

// ---------------------------------------------------------------- main
// LDS: A[8448] B[8192] C[16384] misc[1280] = 34304 floats = 137216 B
__global__ __launch_bounds__(256, 1)
void moe_main(const float* __restrict__ node_features,
              const float* __restrict__ edge_features,
              const float* __restrict__ edge_raw,
              const int* __restrict__ neighbor_list,
              const float* __restrict__ neighbor_mask,
              const float* __restrict__ attn_mask,
              const float* __restrict__ W_edge, const float* __restrict__ b_edge,
              const float* __restrict__ W_node, const float* __restrict__ b_node,
              const float* __restrict__ W_msg, const float* __restrict__ b_msg,
              const float* __restrict__ W_qkv, const float* __restrict__ b_qkv,
              const float* __restrict__ W_out, const float* __restrict__ b_out,
              const float* __restrict__ ln_ffn_g, const float* __restrict__ ln_ffn_b,
              const float* __restrict__ W1n, const float* __restrict__ b1n,
              const float* __restrict__ W2n, const float* __restrict__ b2n,
              const float* __restrict__ W1e, const float* __restrict__ b1e,
              const float* __restrict__ W2e, const float* __restrict__ b2e,
              const float* __restrict__ nh_all,
              const int* __restrict__ work_ne, const float* __restrict__ work_g,
              float* __restrict__ out_node, float* __restrict__ out_edge) {
  extern __shared__ float sm[];
  float* A  = sm;           // 8448: sender -> q^T/ctx^T -> eh2
  float* B  = sm + 8448;    // 8192: nodeh -> msg -> ef
  float* C  = sm + 16640;   // 16384: recv+edge_raw -> k,v -> node-partials -> h1e
  float* MS = sm + 33024;   // misc
  float* Mnh2  = MS + 256;
  float* Mh1   = MS + 512;  // 512
  float* Mmu   = MS + 1024;
  float* Mrstd = MS + 1056;
  float* Mred  = MS + 1088;
  float* Mmask = MS + 1104;

  const int t = threadIdx.x;
  const int pe = work_ne[blockIdx.x];
  const int n = pe >> 3, e = pe & 7;
  const float gate = work_g[blockIdx.x];

  const float* We  = W_edge + (size_t)e * DE_DIM * H_DIM;
  const float* be  = b_edge + e * H_DIM;
  const float* Wn  = W_node + (size_t)e * 2 * H_DIM * H_DIM;
  const float* bn  = b_node + e * H_DIM;
  const float* Wm  = W_msg  + (size_t)e * 2 * H_DIM * H_DIM;
  const float* bm  = b_msg  + e * H_DIM;
  const float* Wq  = W_qkv  + (size_t)e * H_DIM * 3 * H_DIM;
  const float* bq  = b_qkv  + e * 3 * H_DIM;
  const float* Wo  = W_out  + (size_t)e * H_DIM * H_DIM;
  const float* bo  = b_out  + e * H_DIM;
  const float* lfg = ln_ffn_g + e * H_DIM;
  const float* lfb = ln_ffn_b + e * H_DIM;
  const float* w1n = W1n + (size_t)e * H_DIM * FFH;
  const float* c1n = b1n + e * FFH;
  const float* w2n = W2n + (size_t)e * FFH * H_DIM;
  const float* c2n = b2n + e * H_DIM;
  const float* w1e = W1e + (size_t)e * H_DIM * FFH;
  const float* c1e = b1e + e * FFH;
  const float* w2e = W2e + (size_t)e * FFH * H_DIM;
  const float* c2e = b2e + e * H_DIM;

  const int r0 = (t >> 6) * 8;
  const int c0 = (t & 63) * 4;

  // ---- stage: recv->C[0:256], edge_raw->C[256:4352], sender->A, mask ----
  const float* nh_e = nh_all + (size_t)e * N_NODES * H_DIM;
  C[t] = nh_e[n * H_DIM + t];
#pragma unroll
  for (int j = 0; j < 16; ++j)
    C[256 + j * 256 + t] = edge_raw[(size_t)n * K_NB * DE_DIM + j * 256 + t];
  for (int k = 0; k < K_NB; ++k) {
    int row = neighbor_list[n * K_NB + k];
    A[k * H_DIM + t] = nh_e[(size_t)row * H_DIM + t];
  }
  if (t < 32) Mmask[t] = neighbor_mask[n * K_NB + t];
  __syncthreads();

  // ---- phase 1: nodeh = gelu([sender|recv]@Wn + bn) -> B ----
  {
    float rs0 = 0, rs1 = 0, rs2 = 0, rs3 = 0;
    for (int i = 0; i < H_DIM; ++i) {
      float rv = C[i];
      float4 w = *(const float4*)&Wn[(size_t)(H_DIM + i) * H_DIM + c0];
      rs0 += rv * w.x; rs1 += rv * w.y; rs2 += rv * w.z; rs3 += rv * w.w;
    }
    float4 bnv = *(const float4*)&bn[c0];
    float acc[8][4];
#pragma unroll
    for (int r = 0; r < 8; ++r) {
      acc[r][0] = rs0 + bnv.x; acc[r][1] = rs1 + bnv.y;
      acc[r][2] = rs2 + bnv.z; acc[r][3] = rs3 + bnv.w;
    }
    mm_tile<256, 256, 256>(acc, A, r0, Wn, c0);
#pragma unroll
    for (int r = 0; r < 8; ++r)
#pragma unroll
      for (int j = 0; j < 4; ++j)
        B[(r0 + r) * 256 + c0 + j] = gelu_f(acc[r][j]);
  }
  __syncthreads();

  // ---- phase 2: msg_acc = nodeh @ Wm[256:512]; phase 3: eh -> A ----
  float macc[8][4];
#pragma unroll
  for (int r = 0; r < 8; ++r) { macc[r][0] = 0; macc[r][1] = 0; macc[r][2] = 0; macc[r][3] = 0; }
  mm_tile<256, 256, 256>(macc, B, r0, Wm + 256 * 256, c0);
  {
    float4 bev = *(const float4*)&be[c0];
    float acc[8][4];
#pragma unroll
    for (int r = 0; r < 8; ++r) {
      acc[r][0] = bev.x; acc[r][1] = bev.y; acc[r][2] = bev.z; acc[r][3] = bev.w;
    }
    mm_tile<128, 256, 128>(acc, C + 256, r0, We, c0);
#pragma unroll
    for (int r = 0; r < 8; ++r)
#pragma unroll
      for (int j = 0; j < 4; ++j)
        A[(r0 + r) * 256 + c0 + j] = gelu_f(acc[r][j]);
  }
  __syncthreads();

  // ---- phase 4: msg = gelu(msg_acc + eh@Wm[0:256] + bm) -> B ----
  {
    mm_tile<256, 256, 256>(macc, A, r0, Wm, c0);
    float4 bmv = *(const float4*)&bm[c0];
#pragma unroll
    for (int r = 0; r < 8; ++r) {
      B[(r0 + r) * 256 + c0 + 0] = gelu_f(macc[r][0] + bmv.x);
      B[(r0 + r) * 256 + c0 + 1] = gelu_f(macc[r][1] + bmv.y);
      B[(r0 + r) * 256 + c0 + 2] = gelu_f(macc[r][2] + bmv.z);
      B[(r0 + r) * 256 + c0 + 3] = gelu_f(macc[r][3] + bmv.w);
    }
  }
  __syncthreads();

  // ---- phase 5: qkv = msg@Wq + bq ; q transposed->A, k->C[0:8192], v->C[8192:] ----
  {
    float4 bv = *(const float4*)&bq[c0];
    float acc[8][4];
#pragma unroll
    for (int r = 0; r < 8; ++r) { acc[r][0] = bv.x; acc[r][1] = bv.y; acc[r][2] = bv.z; acc[r][3] = bv.w; }
    mm_tile<256, 768, 256>(acc, B, r0, Wq, c0);
#pragma unroll
    for (int r = 0; r < 8; ++r)
#pragma unroll
      for (int j = 0; j < 4; ++j)
        A[(c0 + j) * 33 + r0 + r] = acc[r][j];
  }
  {
    float4 bv = *(const float4*)&bq[256 + c0];
    float acc[8][4];
#pragma unroll
    for (int r = 0; r < 8; ++r) { acc[r][0] = bv.x; acc[r][1] = bv.y; acc[r][2] = bv.z; acc[r][3] = bv.w; }
    mm_tile<256, 768, 256>(acc, B, r0, Wq, 256 + c0);
#pragma unroll
    for (int r = 0; r < 8; ++r)
#pragma unroll
      for (int j = 0; j < 4; ++j)
        C[(r0 + r) * 256 + c0 + j] = acc[r][j];
  }
  {
    float4 bv = *(const float4*)&bq[512 + c0];
    float acc[8][4];
#pragma unroll
    for (int r = 0; r < 8; ++r) { acc[r][0] = bv.x; acc[r][1] = bv.y; acc[r][2] = bv.z; acc[r][3] = bv.w; }
    mm_tile<256, 768, 256>(acc, B, r0, Wq, 512 + c0);
#pragma unroll
    for (int r = 0; r < 8; ++r)
#pragma unroll
      for (int j = 0; j < 4; ++j)
        C[8192 + (r0 + r) * 256 + c0 + j] = acc[r][j];
  }
  __syncthreads();

  // ---- phase 6: attention. thread = (head h, query q) ----
  {
    const int h = t >> 5, q = t & 31;
    float qv[32];
#pragma unroll
    for (int d = 0; d < 32; ++d) qv[d] = A[(h * 32 + d) * 33 + q];
    float s[32];
    const float scale = 0.17677669529663687f;  // 1/sqrt(32)
#pragma unroll
    for (int kk = 0; kk < 32; ++kk) {
      float acc = 0.f;
#pragma unroll
      for (int d4 = 0; d4 < 8; ++d4) {
        float4 kv = *(const float4*)&C[kk * 256 + h * 32 + d4 * 4];
        acc += qv[d4 * 4 + 0] * kv.x + qv[d4 * 4 + 1] * kv.y +
               qv[d4 * 4 + 2] * kv.z + qv[d4 * 4 + 3] * kv.w;
      }
      s[kk] = acc * scale + attn_mask[n * K_NB + kk];
    }
    float m = s[0];
#pragma unroll
    for (int kk = 1; kk < 32; ++kk) m = fmaxf(m, s[kk]);
    float sum = 0.f;
#pragma unroll
    for (int kk = 0; kk < 32; ++kk) { s[kk] = __expf(s[kk] - m); sum += s[kk]; }
    float inv = 1.f / sum;
    __syncthreads();  // all q^T reads done before ctx overwrites A
    float4 cx[8];
#pragma unroll
    for (int d4 = 0; d4 < 8; ++d4) { cx[d4].x = 0; cx[d4].y = 0; cx[d4].z = 0; cx[d4].w = 0; }
#pragma unroll
    for (int kk = 0; kk < 32; ++kk) {
      float w = s[kk] * inv;
#pragma unroll
      for (int d4 = 0; d4 < 8; ++d4) {
        float4 vv = *(const float4*)&C[8192 + kk * 256 + h * 32 + d4 * 4];
        cx[d4].x += w * vv.x; cx[d4].y += w * vv.y; cx[d4].z += w * vv.z; cx[d4].w += w * vv.w;
      }
    }
#pragma unroll
    for (int d4 = 0; d4 < 8; ++d4) {
      A[(h * 32 + d4 * 4 + 0) * 33 + q] = cx[d4].x;
      A[(h * 32 + d4 * 4 + 1) * 33 + q] = cx[d4].y;
      A[(h * 32 + d4 * 4 + 2) * 33 + q] = cx[d4].z;
      A[(h * 32 + d4 * 4 + 3) * 33 + q] = cx[d4].w;
    }
  }
  __syncthreads();

  // ---- phase 7: edge_out = ctx@Wo + bo ; node partials -> C[0:1024]; ef -> B ----
  {
    float4 bv = *(const float4*)&bo[c0];
    float acc[8][4];
#pragma unroll
    for (int r = 0; r < 8; ++r) { acc[r][0] = bv.x; acc[r][1] = bv.y; acc[r][2] = bv.z; acc[r][3] = bv.w; }
    mm_tile_t<256, 256>(acc, A, r0, Wo, c0);
    float np0 = 0, np1 = 0, np2 = 0, np3 = 0;
#pragma unroll
    for (int r = 0; r < 8; ++r) {
      float mk = Mmask[r0 + r];
      np0 += acc[r][0] * mk; np1 += acc[r][1] * mk; np2 += acc[r][2] * mk; np3 += acc[r][3] * mk;
    }
    C[(t >> 6) * 256 + c0 + 0] = np0;
    C[(t >> 6) * 256 + c0 + 1] = np1;
    C[(t >> 6) * 256 + c0 + 2] = np2;
    C[(t >> 6) * 256 + c0 + 3] = np3;
#pragma unroll
    for (int r = 0; r < 8; ++r) {
      float4 efv = *(const float4*)&edge_features[((size_t)n * K_NB + r0 + r) * H_DIM + c0];
      float4 o;
      o.x = acc[r][0] + efv.x; o.y = acc[r][1] + efv.y;
      o.z = acc[r][2] + efv.z; o.w = acc[r][3] + efv.w;
      *(float4*)&B[(r0 + r) * 256 + c0] = o;
    }
  }
  __syncthreads();

  // ---- phase 8: nf + node FFN ----
  float cnt = 1e-5f;
#pragma unroll
  for (int kk = 0; kk < 32; ++kk) cnt += Mmask[kk];
  float nfv;
  {
    float np = C[t] + C[256 + t] + C[512 + t] + C[768 + t];
    nfv = np / cnt + node_features[n * H_DIM + t];
  }
  {
    float sv = nfv, sq = nfv * nfv;
    for (int m = 32; m >= 1; m >>= 1) { sv += __shfl_xor(sv, m, 64); sq += __shfl_xor(sq, m, 64); }
    if ((t & 63) == 0) { Mred[t >> 6] = sv; Mred[4 + (t >> 6)] = sq; }
  }
  __syncthreads();
  {
    float sum = Mred[0] + Mred[1] + Mred[2] + Mred[3];
    float ssum = Mred[4] + Mred[5] + Mred[6] + Mred[7];
    float mu = sum * (1.f / 256.f);
    float var = ssum * (1.f / 256.f) - mu * mu;
    float rstd = rsqrtf(var + 1e-5f);
    Mnh2[t] = (nfv - mu) * rstd * lfg[t] + lfb[t];
  }
  __syncthreads();
  for (int cc = t; cc < FFH; cc += 256) {
    float a = c1n[cc];
    for (int i = 0; i < H_DIM; ++i) a += Mnh2[i] * w1n[(size_t)i * FFH + cc];
    Mh1[cc] = gelu_f(a);
  }
  __syncthreads();
  {
    float o = nfv + c2n[t];
    for (int i = 0; i < FFH; ++i) o += Mh1[i] * w2n[(size_t)i * H_DIM + t];
    atomicAdd(&out_node[n * H_DIM + t], gate * o);
  }

  // ---- phase 9: edge LN: eh2 = LN(ef) -> A ----
  {
    int rr = t >> 3, j = t & 7;
    float s1 = 0, s2 = 0;
    for (int m = 0; m < 32; ++m) {
      float xv = B[rr * 256 + j + 8 * m];
      s1 += xv; s2 += xv * xv;
    }
    s1 += __shfl_xor(s1, 1, 64); s2 += __shfl_xor(s2, 1, 64);
    s1 += __shfl_xor(s1, 2, 64); s2 += __shfl_xor(s2, 2, 64);
    s1 += __shfl_xor(s1, 4, 64); s2 += __shfl_xor(s2, 4, 64);
    if (j == 0) {
      float mu2 = s1 * (1.f / 256.f);
      float v2 = s2 * (1.f / 256.f) - mu2 * mu2;
      Mmu[rr] = mu2; Mrstd[rr] = rsqrtf(v2 + 1e-5f);
    }
  }
  __syncthreads();
  {
    float g2 = lfg[t], b2v = lfb[t];
    for (int r = 0; r < 32; ++r)
      A[r * 256 + t] = (B[r * 256 + t] - Mmu[r]) * Mrstd[r] * g2 + b2v;
  }
  __syncthreads();

  // ---- phase 10: h1e = gelu(eh2@w1e + c1e) -> C [32][512] ----
  for (int half = 0; half < 2; ++half) {
    float4 bv = *(const float4*)&c1e[half * 256 + c0];
    float acc[8][4];
#pragma unroll
    for (int r = 0; r < 8; ++r) { acc[r][0] = bv.x; acc[r][1] = bv.y; acc[r][2] = bv.z; acc[r][3] = bv.w; }
    mm_tile<256, 512, 256>(acc, A, r0, w1e, half * 256 + c0);
#pragma unroll
    for (int r = 0; r < 8; ++r)
#pragma unroll
      for (int j = 0; j < 4; ++j)
        C[(r0 + r) * 512 + half * 256 + c0 + j] = gelu_f(acc[r][j]);
  }
  __syncthreads();

  // ---- phase 11: out_e = ef + h1e@w2e + c2e -> atomic ----
  {
    float4 bv = *(const float4*)&c2e[c0];
    float acc[8][4];
#pragma unroll
    for (int r = 0; r < 8; ++r) { acc[r][0] = bv.x; acc[r][1] = bv.y; acc[r][2] = bv.z; acc[r][3] = bv.w; }
    mm_tile<512, 256, 512>(acc, C, r0, w2e, c0);
#pragma unroll
    for (int r = 0; r < 8; ++r) {
      size_t base = ((size_t)n * K_NB + r0 + r) * H_DIM + c0;
      float4 efv = *(const float4*)&B[(r0 + r) * 256 + c0];
      atomicAdd(&out_edge[base + 0], gate * (acc[r][0] + efv.x));
      atomicAdd(&out_edge[base + 1], gate * (acc[r][1] + efv.y));
      atomicAdd(&out_edge[base + 2], gate * (acc[r][2] + efv.z));
      atomicAdd(&out_edge[base + 3], gate * (acc[r][3] + efv.w));
    }
  }
}

// ---------------------------------------------------------------- launch
extern "C" void kernel_launch(void* const* d_in, const int* in_sizes, int n_in,
                              void* d_out, int out_size, void* d_ws, size_t ws_size,
                              hipStream_t stream) {
  const float* node_features = (const float*)d_in[0];
  const float* edge_features = (const float*)d_in[1];
  const float* edge_raw      = (const float*)d_in[2];
  const int*   neighbor_list = (const int*)d_in[3];
  const float* neighbor_mask = (const float*)d_in[4];
  const float* attn_mask     = (const float*)d_in[5];
  const float* w_gate        = (const float*)d_in[6];
  const float* W_edge = (const float*)d_in[7];
  const float* b_edge = (const float*)d_in[8];
  const float* W_node = (const float*)d_in[9];
  const float* b_node = (const float*)d_in[10];
  const float* W_msg  = (const float*)d_in[11];
  const float* b_msg  = (const float*)d_in[12];
  const float* W_qkv  = (const float*)d_in[13];
  const float* b_qkv  = (const float*)d_in[14];
  const float* W_out  = (const float*)d_in[15];
  const float* b_out  = (const float*)d_in[16];
  const float* ln_attn_g = (const float*)d_in[17];
  const float* ln_attn_b = (const float*)d_in[18];
  const float* ln_ffn_g  = (const float*)d_in[19];
  const float* ln_ffn_b  = (const float*)d_in[20];
  const float* W1n = (const float*)d_in[21];
  const float* b1n = (const float*)d_in[22];
  const float* W2n = (const float*)d_in[23];
  const float* b2n = (const float*)d_in[24];
  const float* W1e = (const float*)d_in[25];
  const float* b1e = (const float*)d_in[26];
  const float* W2e = (const float*)d_in[27];
  const float* b2e = (const float*)d_in[28];

  float* ws = (float*)d_ws;
  float* nh_all  = ws;
  int*   sel_ne  = (int*)(ws + NH_ALL_F);
  float* sel_g   = ws + NH_ALL_F + 2048;
  int*   work_ne = (int*)(ws + NH_ALL_F + 4096);
  float* work_g  = ws + NH_ALL_F + 6144;

  float* out_node = (float*)d_out;
  float* out_edge = out_node + N_NODES * H_DIM;

  hipMemsetAsync(d_out, 0, (size_t)out_size * sizeof(float), stream);

  gate_kernel<<<N_NODES, 64, 0, stream>>>(node_features, w_gate, sel_ne, sel_g);
  sort_kernel<<<1, 256, 0, stream>>>(sel_ne, sel_g, work_ne, work_g);
  nh_kernel<<<dim3(N_NODES, N_EXP), 256, 0, stream>>>(node_features, ln_attn_g, ln_attn_b, nh_all);

  size_t smem = 34304 * sizeof(float);  // 137216 B dynamic LDS
  hipFuncSetAttribute((const void*)moe_main, hipFuncAttributeMaxDynamicSharedMemorySize, (int)smem);
  moe_main<<<N_NODES * NTOPK, 256, smem, stream>>>(
      node_features, edge_features, edge_raw, neighbor_list, neighbor_mask, attn_mask,
      W_edge, b_edge, W_node, b_node, W_msg, b_msg, W_qkv, b_qkv, W_out, b_out,
      ln_ffn_g, ln_ffn_b, W1n, b1n, W2n, b2n, W1e, b1e, W2e, b2e,
      nh_all, work_ne, work_g, out_node, out_edge);
}

// Round 2
// 3685.284 us; speedup vs baseline: 1.3864x; 1.3864x over previous
//
#include <hip/hip_runtime.h>
#include <math.h>

#define N_NODES 1024
#define K_NB    32
#define H_DIM   256
#define DE_DIM  128
#define N_EXP   8
#define NTOPK   2
#define FFH     512

#define NH_ALL_F (N_EXP * N_NODES * H_DIM)  // 2097152 floats

// ---------------------------------------------------------------- helpers
__device__ __forceinline__ float gelu_f(float x) {
  // jax.nn.gelu default approximate=True (tanh form)
  float u = 0.7978845608028654f * (x + 0.044715f * x * x * x);
  float ex = __expf(2.f * u);
  float th = 1.f - 2.f / (ex + 1.f);   // tanh(u), inf-safe
  return 0.5f * x * (1.f + th);
}

// acc[r][j] += sum_i Xl[(r0+r)*XS + i] * W[i*LDW + c0 + j],  j in {0,1}
// Xl reads are wave-uniform (broadcast); W reads are lane-coalesced float2.
template<int R, int CIN, int LDW, int XS>
__device__ __forceinline__ void mm2(float acc[R][2], const float* Xl, int r0,
                                    const float* __restrict__ W, int c0) {
#pragma unroll 2
  for (int i = 0; i < CIN; i += 4) {
    float2 w0 = *(const float2*)&W[(size_t)(i + 0) * LDW + c0];
    float2 w1 = *(const float2*)&W[(size_t)(i + 1) * LDW + c0];
    float2 w2 = *(const float2*)&W[(size_t)(i + 2) * LDW + c0];
    float2 w3 = *(const float2*)&W[(size_t)(i + 3) * LDW + c0];
#pragma unroll
    for (int r = 0; r < R; ++r) {
      float4 xv = *(const float4*)&Xl[(r0 + r) * XS + i];
      acc[r][0] += xv.x * w0.x + xv.y * w1.x + xv.z * w2.x + xv.w * w3.x;
      acc[r][1] += xv.x * w0.y + xv.y * w1.y + xv.z * w2.y + xv.w * w3.y;
    }
  }
}

// ---------------------------------------------------------------- gating
__global__ __launch_bounds__(64)
void gate_kernel(const float* __restrict__ nf, const float* __restrict__ wg,
                 int* __restrict__ sel_ne, float* __restrict__ sel_g) {
  int n = blockIdx.x, t = threadIdx.x;
  float p[8] = {0, 0, 0, 0, 0, 0, 0, 0};
  for (int j = 0; j < 4; ++j) {
    float x = nf[n * H_DIM + t + 64 * j];
#pragma unroll
    for (int e = 0; e < 8; ++e) p[e] += x * wg[(t + 64 * j) * 8 + e];
  }
#pragma unroll
  for (int e = 0; e < 8; ++e)
    for (int m = 32; m >= 1; m >>= 1) p[e] += __shfl_xor(p[e], m, 64);
  if (t == 0) {
    int i0 = 0; float v0 = p[0];
    for (int e = 1; e < 8; ++e) if (p[e] > v0) { v0 = p[e]; i0 = e; }
    int i1 = -1; float v1 = -3.4e38f;
    for (int e = 0; e < 8; ++e) if (e != i0 && p[e] > v1) { v1 = p[e]; i1 = e; }
    float g1 = __expf(v1 - v0);
    float inv = 1.f / (1.f + g1);
    sel_ne[n * 2 + 0] = (n << 3) | i0; sel_g[n * 2 + 0] = inv;
    sel_ne[n * 2 + 1] = (n << 3) | i1; sel_g[n * 2 + 1] = g1 * inv;
  }
}

__global__ __launch_bounds__(256)
void sort_kernel(const int* __restrict__ sel_ne, const float* __restrict__ sel_g,
                 int* __restrict__ work_ne, float* __restrict__ work_g) {
  __shared__ int cnt[8], off[8], cur[8];
  int t = threadIdx.x;
  if (t < 8) { cnt[t] = 0; cur[t] = 0; }
  __syncthreads();
  for (int i = t; i < N_NODES * NTOPK; i += 256) atomicAdd(&cnt[sel_ne[i] & 7], 1);
  __syncthreads();
  if (t == 0) { int s = 0; for (int e = 0; e < 8; ++e) { off[e] = s; s += cnt[e]; } }
  __syncthreads();
  for (int i = t; i < N_NODES * NTOPK; i += 256) {
    int pe = sel_ne[i]; int e = pe & 7;
    int pos = off[e] + atomicAdd(&cur[e], 1);
    work_ne[pos] = pe; work_g[pos] = sel_g[i];
  }
}

// per-expert LayerNorm of all nodes (ln_attn params)
__global__ __launch_bounds__(256)
void nh_kernel(const float* __restrict__ nf, const float* __restrict__ lag,
               const float* __restrict__ lab, float* __restrict__ nh_all) {
  __shared__ float red[8];
  int n = blockIdx.x, e = blockIdx.y, t = threadIdx.x;
  float x = nf[n * H_DIM + t];
  float sv = x, sq = x * x;
  for (int m = 32; m >= 1; m >>= 1) { sv += __shfl_xor(sv, m, 64); sq += __shfl_xor(sq, m, 64); }
  if ((t & 63) == 0) { red[t >> 6] = sv; red[4 + (t >> 6)] = sq; }
  __syncthreads();
  float sum = red[0] + red[1] + red[2] + red[3];
  float ssum = red[4] + red[5] + red[6] + red[7];
  float mu = sum * (1.f / 256.f);
  float var = ssum * (1.f / 256.f) - mu * mu;
  float rstd = rsqrtf(var + 1e-5f);
  nh_all[((size_t)e * N_NODES + n) * H_DIM + t] =
      (x - mu) * rstd * lag[e * H_DIM + t] + lab[e * H_DIM + t];
}

// ---------------------------------------------------------------- main
// 1024 threads = 16 waves = 4 waves/SIMD (latency hiding; was 1 wave/SIMD).
// LDS: A[8448] B[8192] C[16384] misc[1024] = 34048 floats = 136192 B, 1 block/CU.
__global__ __launch_bounds__(1024)
void moe_main(const float* __restrict__ node_features,
              const float* __restrict__ edge_features,
              const float* __restrict__ edge_raw,
              const int* __restrict__ neighbor_list,
              const float* __restrict__ neighbor_mask,
              const float* __restrict__ W_edge, const float* __restrict__ b_edge,
              const float* __restrict__ W_node, const float* __restrict__ b_node,
              const float* __restrict__ W_msg, const float* __restrict__ b_msg,
              const float* __restrict__ W_qkv, const float* __restrict__ b_qkv,
              const float* __restrict__ W_out, const float* __restrict__ b_out,
              const float* __restrict__ ln_ffn_g, const float* __restrict__ ln_ffn_b,
              const float* __restrict__ W1n, const float* __restrict__ b1n,
              const float* __restrict__ W2n, const float* __restrict__ b2n,
              const float* __restrict__ W1e, const float* __restrict__ b1e,
              const float* __restrict__ W2e, const float* __restrict__ b2e,
              const float* __restrict__ nh_all,
              const int* __restrict__ work_ne, const float* __restrict__ work_g,
              float* __restrict__ out_node, float* __restrict__ out_edge) {
  extern __shared__ float sm[];
  float* A  = sm;           // 8448: sender -> eh -> q^T/ctx^T -> eh2
  float* B  = sm + 8448;    // 8192: nodeh -> msg -> ef
  float* C  = sm + 16640;   // 16384: recv+edge_raw -> k,v -> node-partials -> h1e
  float* MS = sm + 33024;   // misc: 1024 floats
  float* Mnh2  = MS;        // 256
  float* Mh1   = MS + 256;  // 512
  float* Mmu   = MS + 768;  // 32
  float* Mrstd = MS + 800;  // 32
  float* Mred  = MS + 832;  // 8
  float* Mmask = MS + 840;  // 32

  const int t = threadIdx.x;
  const int pe = work_ne[blockIdx.x];
  const int n = pe >> 3, e = pe & 7;
  const float gate = work_g[blockIdx.x];

  const float* We  = W_edge + (size_t)e * DE_DIM * H_DIM;
  const float* be  = b_edge + e * H_DIM;
  const float* Wn  = W_node + (size_t)e * 2 * H_DIM * H_DIM;
  const float* bn  = b_node + e * H_DIM;
  const float* Wm  = W_msg  + (size_t)e * 2 * H_DIM * H_DIM;
  const float* bm  = b_msg  + e * H_DIM;
  const float* Wq  = W_qkv  + (size_t)e * H_DIM * 3 * H_DIM;
  const float* bq  = b_qkv  + e * 3 * H_DIM;
  const float* Wo  = W_out  + (size_t)e * H_DIM * H_DIM;
  const float* bo  = b_out  + e * H_DIM;
  const float* lfg = ln_ffn_g + e * H_DIM;
  const float* lfb = ln_ffn_b + e * H_DIM;
  const float* w1n = W1n + (size_t)e * H_DIM * FFH;
  const float* c1n = b1n + e * FFH;
  const float* w2n = W2n + (size_t)e * FFH * H_DIM;
  const float* c2n = b2n + e * H_DIM;
  const float* w1e = W1e + (size_t)e * H_DIM * FFH;
  const float* c1e = b1e + e * FFH;
  const float* w2e = W2e + (size_t)e * FFH * H_DIM;
  const float* c2e = b2e + e * H_DIM;

  // matmul tiling: 16 waves = 8 rowgroups(4 rows) x 2 colgroups(128 cols)
  const int w  = t >> 6, lane = t & 63;
  const int rg = w >> 1, cg = w & 1;
  const int r0 = rg * 4;
  const int c0 = cg * 128 + lane * 2;

  // ---- stage: recv->C[0:256], edge_raw->C[256:4352], sender->A, mask ----
  const float* nh_e = nh_all + (size_t)e * N_NODES * H_DIM;
  if (t < H_DIM) C[t] = nh_e[n * H_DIM + t];
#pragma unroll
  for (int j = 0; j < 4; ++j)
    C[256 + j * 1024 + t] = edge_raw[(size_t)n * K_NB * DE_DIM + j * 1024 + t];
  {
    int col = t & 255, grp = t >> 8;
#pragma unroll
    for (int j = 0; j < 8; ++j) {
      int krow = grp * 8 + j;
      int row = neighbor_list[n * K_NB + krow];
      A[krow * H_DIM + col] = nh_e[(size_t)row * H_DIM + col];
    }
  }
  if (t < 32) Mmask[t] = neighbor_mask[n * K_NB + t];
  __syncthreads();

  // ---- phase 1: nodeh = gelu([sender|recv]@Wn + bn) -> B ----
  {
    float rs0 = 0.f, rs1 = 0.f;
    for (int i = 0; i < H_DIM; ++i) {
      float rv = C[i];
      float2 wv = *(const float2*)&Wn[(size_t)(H_DIM + i) * H_DIM + c0];
      rs0 += rv * wv.x; rs1 += rv * wv.y;
    }
    float2 bnv = *(const float2*)&bn[c0];
    float acc[4][2];
#pragma unroll
    for (int r = 0; r < 4; ++r) { acc[r][0] = rs0 + bnv.x; acc[r][1] = rs1 + bnv.y; }
    mm2<4, 256, 256, 256>(acc, A, r0, Wn, c0);
#pragma unroll
    for (int r = 0; r < 4; ++r)
      *(float2*)&B[(r0 + r) * 256 + c0] = make_float2(gelu_f(acc[r][0]), gelu_f(acc[r][1]));
  }
  __syncthreads();

  // ---- phase 2: msg_acc = nodeh@Wm[256:512]; phase 3: eh -> A ----
  float macc[4][2];
#pragma unroll
  for (int r = 0; r < 4; ++r) { macc[r][0] = 0.f; macc[r][1] = 0.f; }
  mm2<4, 256, 256, 256>(macc, B, r0, Wm + 256 * 256, c0);
  {
    float2 bev = *(const float2*)&be[c0];
    float acc[4][2];
#pragma unroll
    for (int r = 0; r < 4; ++r) { acc[r][0] = bev.x; acc[r][1] = bev.y; }
    mm2<4, 128, 256, 128>(acc, C + 256, r0, We, c0);
#pragma unroll
    for (int r = 0; r < 4; ++r)
      *(float2*)&A[(r0 + r) * 256 + c0] = make_float2(gelu_f(acc[r][0]), gelu_f(acc[r][1]));
  }
  __syncthreads();

  // ---- phase 4: msg = gelu(msg_acc + eh@Wm[0:256] + bm) -> B ----
  {
    mm2<4, 256, 256, 256>(macc, A, r0, Wm, c0);
    float2 bmv = *(const float2*)&bm[c0];
#pragma unroll
    for (int r = 0; r < 4; ++r)
      *(float2*)&B[(r0 + r) * 256 + c0] =
          make_float2(gelu_f(macc[r][0] + bmv.x), gelu_f(macc[r][1] + bmv.y));
  }
  __syncthreads();

  // ---- phase 5: qkv = msg@Wq + bq; q^T->A (stride 33), k->C[0:8192], v->C[8192:] ----
  {
    float2 bv = *(const float2*)&bq[c0];
    float acc[4][2];
#pragma unroll
    for (int r = 0; r < 4; ++r) { acc[r][0] = bv.x; acc[r][1] = bv.y; }
    mm2<4, 256, 768, 256>(acc, B, r0, Wq, c0);
#pragma unroll
    for (int r = 0; r < 4; ++r) {
      A[(c0 + 0) * 33 + r0 + r] = acc[r][0];
      A[(c0 + 1) * 33 + r0 + r] = acc[r][1];
    }
  }
  {
    float2 bv = *(const float2*)&bq[256 + c0];
    float acc[4][2];
#pragma unroll
    for (int r = 0; r < 4; ++r) { acc[r][0] = bv.x; acc[r][1] = bv.y; }
    mm2<4, 256, 768, 256>(acc, B, r0, Wq, 256 + c0);
#pragma unroll
    for (int r = 0; r < 4; ++r)
      *(float2*)&C[(r0 + r) * 256 + c0] = make_float2(acc[r][0], acc[r][1]);
  }
  {
    float2 bv = *(const float2*)&bq[512 + c0];
    float acc[4][2];
#pragma unroll
    for (int r = 0; r < 4; ++r) { acc[r][0] = bv.x; acc[r][1] = bv.y; }
    mm2<4, 256, 768, 256>(acc, B, r0, Wq, 512 + c0);
#pragma unroll
    for (int r = 0; r < 4; ++r)
      *(float2*)&C[8192 + (r0 + r) * 256 + c0] = make_float2(acc[r][0], acc[r][1]);
  }
  __syncthreads();

  // ---- phase 6: attention; only t<256 active (h=t>>5, q=t&31), s[32] in regs ----
  float s[32];
  const int hh = (t >> 5) & 7, qq = t & 31;
  if (t < 256) {
#pragma unroll
    for (int kk = 0; kk < 32; ++kk) s[kk] = 0.f;
#pragma unroll
    for (int d4 = 0; d4 < 8; ++d4) {
      float q0 = A[(hh * 32 + d4 * 4 + 0) * 33 + qq];
      float q1 = A[(hh * 32 + d4 * 4 + 1) * 33 + qq];
      float q2 = A[(hh * 32 + d4 * 4 + 2) * 33 + qq];
      float q3 = A[(hh * 32 + d4 * 4 + 3) * 33 + qq];
#pragma unroll
      for (int kk = 0; kk < 32; ++kk) {
        float4 kv = *(const float4*)&C[kk * 256 + hh * 32 + d4 * 4];
        s[kk] += q0 * kv.x + q1 * kv.y + q2 * kv.z + q3 * kv.w;
      }
    }
    const float scale = 0.17677669529663687f;  // 1/sqrt(32)
    float m = -3.4e38f;
#pragma unroll
    for (int kk = 0; kk < 32; ++kk) {
      float mv = (Mmask[kk] > 0.f) ? 0.f : -1e9f;
      s[kk] = s[kk] * scale + mv;
      m = fmaxf(m, s[kk]);
    }
    float sum = 0.f;
#pragma unroll
    for (int kk = 0; kk < 32; ++kk) { s[kk] = __expf(s[kk] - m); sum += s[kk]; }
    float inv = 1.f / sum;
#pragma unroll
    for (int kk = 0; kk < 32; ++kk) s[kk] *= inv;
  }
  __syncthreads();  // all q^T reads done before ctx overwrites A
  if (t < 256) {
#pragma unroll
    for (int d4 = 0; d4 < 8; ++d4) {
      float x0 = 0.f, x1 = 0.f, x2 = 0.f, x3 = 0.f;
#pragma unroll
      for (int kk = 0; kk < 32; ++kk) {
        float4 vv = *(const float4*)&C[8192 + kk * 256 + hh * 32 + d4 * 4];
        x0 += s[kk] * vv.x; x1 += s[kk] * vv.y; x2 += s[kk] * vv.z; x3 += s[kk] * vv.w;
      }
      A[(hh * 32 + d4 * 4 + 0) * 33 + qq] = x0;
      A[(hh * 32 + d4 * 4 + 1) * 33 + qq] = x1;
      A[(hh * 32 + d4 * 4 + 2) * 33 + qq] = x2;
      A[(hh * 32 + d4 * 4 + 3) * 33 + qq] = x3;
    }
  }
  __syncthreads();

  // ---- phase 7: edge_out = ctx@Wo + bo; node partials -> C[0:2048]; ef -> B ----
  {
    float2 bv = *(const float2*)&bo[c0];
    float acc[4][2];
#pragma unroll
    for (int r = 0; r < 4; ++r) { acc[r][0] = bv.x; acc[r][1] = bv.y; }
#pragma unroll 4
    for (int i = 0; i < 256; i += 2) {
      float2 w0 = *(const float2*)&Wo[(size_t)(i + 0) * 256 + c0];
      float2 w1 = *(const float2*)&Wo[(size_t)(i + 1) * 256 + c0];
#pragma unroll
      for (int r = 0; r < 4; ++r) {
        float x0 = A[(i + 0) * 33 + r0 + r];
        float x1 = A[(i + 1) * 33 + r0 + r];
        acc[r][0] += x0 * w0.x + x1 * w1.x;
        acc[r][1] += x0 * w0.y + x1 * w1.y;
      }
    }
    float np0 = 0.f, np1 = 0.f;
#pragma unroll
    for (int r = 0; r < 4; ++r) {
      float mk = Mmask[r0 + r];
      np0 += acc[r][0] * mk; np1 += acc[r][1] * mk;
    }
    *(float2*)&C[rg * 256 + c0] = make_float2(np0, np1);
#pragma unroll
    for (int r = 0; r < 4; ++r) {
      float2 efv = *(const float2*)&edge_features[((size_t)n * K_NB + r0 + r) * H_DIM + c0];
      *(float2*)&B[(r0 + r) * 256 + c0] = make_float2(acc[r][0] + efv.x, acc[r][1] + efv.y);
    }
  }
  __syncthreads();

  // ---- phase 8: nf + node FFN (t<256 / t<512 lanes active) ----
  float cnt = 1e-5f;
#pragma unroll
  for (int kk = 0; kk < 32; ++kk) cnt += Mmask[kk];
  float nfv = 0.f;
  if (t < 256) {
    float np = 0.f;
#pragma unroll
    for (int g = 0; g < 8; ++g) np += C[g * 256 + t];
    nfv = np / cnt + node_features[n * H_DIM + t];
    float sv = nfv, sq = nfv * nfv;
    for (int m = 32; m >= 1; m >>= 1) { sv += __shfl_xor(sv, m, 64); sq += __shfl_xor(sq, m, 64); }
    if ((t & 63) == 0) { Mred[t >> 6] = sv; Mred[4 + (t >> 6)] = sq; }
  }
  __syncthreads();
  if (t < 256) {
    float sum = Mred[0] + Mred[1] + Mred[2] + Mred[3];
    float ssum = Mred[4] + Mred[5] + Mred[6] + Mred[7];
    float mu = sum * (1.f / 256.f);
    float var = ssum * (1.f / 256.f) - mu * mu;
    float rstd = rsqrtf(var + 1e-5f);
    Mnh2[t] = (nfv - mu) * rstd * lfg[t] + lfb[t];
  }
  __syncthreads();
  if (t < FFH) {
    float a = c1n[t];
    for (int i = 0; i < H_DIM; ++i) a += Mnh2[i] * w1n[(size_t)i * FFH + t];
    Mh1[t] = gelu_f(a);
  }
  __syncthreads();
  if (t < 256) {
    float o = nfv + c2n[t];
    for (int i = 0; i < FFH; ++i) o += Mh1[i] * w2n[(size_t)i * H_DIM + t];
    atomicAdd(&out_node[n * H_DIM + t], gate * o);
  }

  // ---- phase 9: edge LN: eh2 = LN(ef) -> A ----
  {
    int rr = t >> 5, j = t & 31;
    float s1 = 0.f, s2 = 0.f;
#pragma unroll
    for (int m2 = 0; m2 < 8; ++m2) {
      float xv = B[rr * 256 + j + 32 * m2];
      s1 += xv; s2 += xv * xv;
    }
    s1 += __shfl_xor(s1, 16, 32); s2 += __shfl_xor(s2, 16, 32);
    s1 += __shfl_xor(s1, 8, 32);  s2 += __shfl_xor(s2, 8, 32);
    s1 += __shfl_xor(s1, 4, 32);  s2 += __shfl_xor(s2, 4, 32);
    s1 += __shfl_xor(s1, 2, 32);  s2 += __shfl_xor(s2, 2, 32);
    s1 += __shfl_xor(s1, 1, 32);  s2 += __shfl_xor(s2, 1, 32);
    if (j == 0) {
      float mu2 = s1 * (1.f / 256.f);
      float v2 = s2 * (1.f / 256.f) - mu2 * mu2;
      Mmu[rr] = mu2; Mrstd[rr] = rsqrtf(v2 + 1e-5f);
    }
  }
  __syncthreads();
  {
    int col = t & 255, rgp = t >> 8;
    float g2 = lfg[col], b2v = lfb[col];
#pragma unroll
    for (int r = 0; r < 8; ++r) {
      int row = rgp * 8 + r;
      A[row * 256 + col] = (B[row * 256 + col] - Mmu[row]) * Mrstd[row] * g2 + b2v;
    }
  }
  __syncthreads();

  // ---- phase 10: h1e = gelu(eh2@w1e + c1e) -> C [32][512] ----
#pragma unroll
  for (int half = 0; half < 2; ++half) {
    float2 bv = *(const float2*)&c1e[half * 256 + c0];
    float acc[4][2];
#pragma unroll
    for (int r = 0; r < 4; ++r) { acc[r][0] = bv.x; acc[r][1] = bv.y; }
    mm2<4, 256, 512, 256>(acc, A, r0, w1e, half * 256 + c0);
#pragma unroll
    for (int r = 0; r < 4; ++r)
      *(float2*)&C[(r0 + r) * 512 + half * 256 + c0] =
          make_float2(gelu_f(acc[r][0]), gelu_f(acc[r][1]));
  }
  __syncthreads();

  // ---- phase 11: out_e = ef + h1e@w2e + c2e -> atomic ----
  {
    float2 bv = *(const float2*)&c2e[c0];
    float acc[4][2];
#pragma unroll
    for (int r = 0; r < 4; ++r) { acc[r][0] = bv.x; acc[r][1] = bv.y; }
    mm2<4, 512, 256, 512>(acc, C, r0, w2e, c0);
#pragma unroll
    for (int r = 0; r < 4; ++r) {
      size_t base = ((size_t)n * K_NB + r0 + r) * H_DIM + c0;
      float2 efv = *(const float2*)&B[(r0 + r) * 256 + c0];
      atomicAdd(&out_edge[base + 0], gate * (acc[r][0] + efv.x));
      atomicAdd(&out_edge[base + 1], gate * (acc[r][1] + efv.y));
    }
  }
}

// ---------------------------------------------------------------- launch
extern "C" void kernel_launch(void* const* d_in, const int* in_sizes, int n_in,
                              void* d_out, int out_size, void* d_ws, size_t ws_size,
                              hipStream_t stream) {
  const float* node_features = (const float*)d_in[0];
  const float* edge_features = (const float*)d_in[1];
  const float* edge_raw      = (const float*)d_in[2];
  const int*   neighbor_list = (const int*)d_in[3];
  const float* neighbor_mask = (const float*)d_in[4];
  // d_in[5] = attn_mask (recomputed from neighbor_mask on the fly)
  const float* w_gate        = (const float*)d_in[6];
  const float* W_edge = (const float*)d_in[7];
  const float* b_edge = (const float*)d_in[8];
  const float* W_node = (const float*)d_in[9];
  const float* b_node = (const float*)d_in[10];
  const float* W_msg  = (const float*)d_in[11];
  const float* b_msg  = (const float*)d_in[12];
  const float* W_qkv  = (const float*)d_in[13];
  const float* b_qkv  = (const float*)d_in[14];
  const float* W_out  = (const float*)d_in[15];
  const float* b_out  = (const float*)d_in[16];
  const float* ln_attn_g = (const float*)d_in[17];
  const float* ln_attn_b = (const float*)d_in[18];
  const float* ln_ffn_g  = (const float*)d_in[19];
  const float* ln_ffn_b  = (const float*)d_in[20];
  const float* W1n = (const float*)d_in[21];
  const float* b1n = (const float*)d_in[22];
  const float* W2n = (const float*)d_in[23];
  const float* b2n = (const float*)d_in[24];
  const float* W1e = (const float*)d_in[25];
  const float* b1e = (const float*)d_in[26];
  const float* W2e = (const float*)d_in[27];
  const float* b2e = (const float*)d_in[28];

  float* ws = (float*)d_ws;
  float* nh_all  = ws;
  int*   sel_ne  = (int*)(ws + NH_ALL_F);
  float* sel_g   = ws + NH_ALL_F + 2048;
  int*   work_ne = (int*)(ws + NH_ALL_F + 4096);
  float* work_g  = ws + NH_ALL_F + 6144;

  float* out_node = (float*)d_out;
  float* out_edge = out_node + N_NODES * H_DIM;

  hipMemsetAsync(d_out, 0, (size_t)out_size * sizeof(float), stream);

  gate_kernel<<<N_NODES, 64, 0, stream>>>(node_features, w_gate, sel_ne, sel_g);
  sort_kernel<<<1, 256, 0, stream>>>(sel_ne, sel_g, work_ne, work_g);
  nh_kernel<<<dim3(N_NODES, N_EXP), 256, 0, stream>>>(node_features, ln_attn_g, ln_attn_b, nh_all);

  size_t smem = 34048 * sizeof(float);  // 136192 B dynamic LDS
  hipFuncSetAttribute((const void*)moe_main, hipFuncAttributeMaxDynamicSharedMemorySize, (int)smem);
  moe_main<<<N_NODES * NTOPK, 1024, smem, stream>>>(
      node_features, edge_features, edge_raw, neighbor_list, neighbor_mask,
      W_edge, b_edge, W_node, b_node, W_msg, b_msg, W_qkv, b_qkv, W_out, b_out,
      ln_ffn_g, ln_ffn_b, W1n, b1n, W2n, b2n, W1e, b1e, W2e, b2e,
      nh_all, work_ne, work_g, out_node, out_edge);
}

// Round 3
// 841.399 us; speedup vs baseline: 6.0721x; 4.3799x over previous
//
#include <hip/hip_runtime.h>
#include <math.h>

#define N_NODES 1024
#define K_NB    32
#define H_DIM   256
#define DE_DIM  128
#define N_EXP   8
#define NTOPK   2
#define FFH     512

typedef __attribute__((ext_vector_type(8))) short s8v;   // 8 bf16 = 4 VGPR
typedef __attribute__((ext_vector_type(4))) float f4v;   // MFMA acc

// ---- ws layout (elements) ----
#define NH_ELEMS   (N_EXP * N_NODES * H_DIM)   // 2097152 bf16
// per-expert fragment-pool offsets (bf16 elems)
#define OFF_WN   0
#define OFF_WM   65536
#define OFF_WE   196608
#define OFF_WQ   229376
#define OFF_WO   425984
#define OFF_W1E  491520
#define OFF_W2E  622592
#define EXP_STRIDE 753664

// ---------------------------------------------------------------- helpers
__device__ __forceinline__ unsigned short f2bf(float x) {
  unsigned u = __float_as_uint(x);
  unsigned r = u + 0x7FFFu + ((u >> 16) & 1u);   // RNE
  return (unsigned short)(r >> 16);
}
__device__ __forceinline__ float bf2f(unsigned short h) {
  return __uint_as_float((unsigned)h << 16);
}
__device__ __forceinline__ float gelu_f(float x) {
  float u = 0.7978845608028654f * (x + 0.044715f * x * x * x);
  float ex = __expf(2.f * u);
  float th = 1.f - 2.f / (ex + 1.f);
  return 0.5f * x * (1.f + th);
}

// A-fragment read from row-major bf16 LDS tile with XOR swizzle.
// lane l: row = rt*16+(l&15), k-bytes = kt*64 + (l>>4)*16
__device__ __forceinline__ s8v lda(const char* base, int SBv, int rt, int kt, int l) {
  int r = rt * 16 + (l & 15);
  int byte = r * SBv + kt * 64 + ((l >> 4) << 4);
  return *(const s8v*)(base + (byte ^ ((r & 7) << 4)));
}
// bf16 store into swizzled row-major tile
__device__ __forceinline__ void stb16(char* base, int SBv, int r, int c, float v) {
  *(unsigned short*)(base + ((r * SBv + c * 2) ^ ((r & 7) << 4))) = f2bf(v);
}

// K-loop: NA output tiles (ct = ctb + 8*m), NKT k-steps; B frags from global pool.
template<int NA, int NKT>
__device__ __forceinline__ void kloop(f4v acc[NA], const char* Ab, int ASB, int rt,
                                      const unsigned short* __restrict__ fb, int NCT,
                                      int ktb0, int ctb, int l) {
  for (int kt = 0; kt < NKT; ++kt) {
    s8v av = lda(Ab, ASB, rt, kt, l);
#pragma unroll
    for (int m = 0; m < NA; ++m) {
      s8v bv = *(const s8v*)(fb + (((size_t)(ktb0 + kt) * NCT + (ctb + 8 * m)) * 64 + l) * 8);
      acc[m] = __builtin_amdgcn_mfma_f32_16x16x32_bf16(av, bv, acc[m], 0, 0, 0);
    }
  }
}

// ---------------------------------------------------------------- gating
__global__ __launch_bounds__(64)
void gate_kernel(const float* __restrict__ nf, const float* __restrict__ wg,
                 int* __restrict__ sel_ne, float* __restrict__ sel_g) {
  int n = blockIdx.x, t = threadIdx.x;
  float p[8] = {0, 0, 0, 0, 0, 0, 0, 0};
  for (int j = 0; j < 4; ++j) {
    float x = nf[n * H_DIM + t + 64 * j];
#pragma unroll
    for (int e = 0; e < 8; ++e) p[e] += x * wg[(t + 64 * j) * 8 + e];
  }
#pragma unroll
  for (int e = 0; e < 8; ++e)
    for (int m = 32; m >= 1; m >>= 1) p[e] += __shfl_xor(p[e], m, 64);
  if (t == 0) {
    int i0 = 0; float v0 = p[0];
    for (int e = 1; e < 8; ++e) if (p[e] > v0) { v0 = p[e]; i0 = e; }
    int i1 = -1; float v1 = -3.4e38f;
    for (int e = 0; e < 8; ++e) if (e != i0 && p[e] > v1) { v1 = p[e]; i1 = e; }
    float g1 = __expf(v1 - v0);
    float inv = 1.f / (1.f + g1);
    sel_ne[n * 2 + 0] = (n << 3) | i0; sel_g[n * 2 + 0] = inv;
    sel_ne[n * 2 + 1] = (n << 3) | i1; sel_g[n * 2 + 1] = g1 * inv;
  }
}

__global__ __launch_bounds__(256)
void sort_kernel(const int* __restrict__ sel_ne, const float* __restrict__ sel_g,
                 int* __restrict__ work_ne, float* __restrict__ work_g) {
  __shared__ int cnt[8], off[8], cur[8];
  int t = threadIdx.x;
  if (t < 8) { cnt[t] = 0; cur[t] = 0; }
  __syncthreads();
  for (int i = t; i < N_NODES * NTOPK; i += 256) atomicAdd(&cnt[sel_ne[i] & 7], 1);
  __syncthreads();
  if (t == 0) { int s = 0; for (int e = 0; e < 8; ++e) { off[e] = s; s += cnt[e]; } }
  __syncthreads();
  for (int i = t; i < N_NODES * NTOPK; i += 256) {
    int pe = sel_ne[i]; int e = pe & 7;
    int pos = off[e] + atomicAdd(&cur[e], 1);
    work_ne[pos] = pe; work_g[pos] = sel_g[i];
  }
}

// per-expert LayerNorm of all nodes -> bf16
__global__ __launch_bounds__(256)
void nh_kernel(const float* __restrict__ nf, const float* __restrict__ lag,
               const float* __restrict__ lab, unsigned short* __restrict__ nh16) {
  __shared__ float red[8];
  int n = blockIdx.x, e = blockIdx.y, t = threadIdx.x;
  float x = nf[n * H_DIM + t];
  float sv = x, sq = x * x;
  for (int m = 32; m >= 1; m >>= 1) { sv += __shfl_xor(sv, m, 64); sq += __shfl_xor(sq, m, 64); }
  if ((t & 63) == 0) { red[t >> 6] = sv; red[4 + (t >> 6)] = sq; }
  __syncthreads();
  float sum = red[0] + red[1] + red[2] + red[3];
  float ssum = red[4] + red[5] + red[6] + red[7];
  float mu = sum * (1.f / 256.f);
  float var = ssum * (1.f / 256.f) - mu * mu;
  float rstd = rsqrtf(var + 1e-5f);
  nh16[((size_t)e * N_NODES + n) * H_DIM + t] =
      f2bf((x - mu) * rstd * lag[e * H_DIM + t] + lab[e * H_DIM + t]);
}

// ------------------------------------------------ weight -> bf16 fragments
// one wave per fragment; lane l: 8 elems W[kt*32+(l>>4)*8+j][ct*16+(l&15)]
__global__ __launch_bounds__(64)
void wconv(const float* __restrict__ W_node, const float* __restrict__ W_msg,
           const float* __restrict__ W_edge, const float* __restrict__ W_qkv,
           const float* __restrict__ W_out, const float* __restrict__ W1e,
           const float* __restrict__ W2e, unsigned short* __restrict__ fb) {
  int f = blockIdx.x, e = blockIdx.y, l = threadIdx.x;
  const float* src; int C, nct, fl; size_t off;
  if (f < 128)       { src = W_node + (size_t)e * 131072; C = 256; nct = 16; fl = f;        off = OFF_WN;  }
  else if (f < 384)  { src = W_msg  + (size_t)e * 131072; C = 256; nct = 16; fl = f - 128;  off = OFF_WM;  }
  else if (f < 448)  { src = W_edge + (size_t)e * 32768;  C = 256; nct = 16; fl = f - 384;  off = OFF_WE;  }
  else if (f < 832)  { src = W_qkv  + (size_t)e * 196608; C = 768; nct = 48; fl = f - 448;  off = OFF_WQ;  }
  else if (f < 960)  { src = W_out  + (size_t)e * 65536;  C = 256; nct = 16; fl = f - 832;  off = OFF_WO;  }
  else if (f < 1216) { src = W1e    + (size_t)e * 131072; C = 512; nct = 32; fl = f - 960;  off = OFF_W1E; }
  else               { src = W2e    + (size_t)e * 131072; C = 256; nct = 16; fl = f - 1216; off = OFF_W2E; }
  int kt = fl / nct, ct = fl - kt * nct;
  int k0 = kt * 32 + ((l >> 4) << 3), c = ct * 16 + (l & 15);
  unsigned pk[4];
#pragma unroll
  for (int jj = 0; jj < 4; ++jj) {
    unsigned short a = f2bf(src[(size_t)(k0 + 2 * jj) * C + c]);
    unsigned short b = f2bf(src[(size_t)(k0 + 2 * jj + 1) * C + c]);
    pk[jj] = (unsigned)a | ((unsigned)b << 16);
  }
  unsigned short* dst = fb + (size_t)e * EXP_STRIDE + off + ((size_t)fl * 64 + l) * 8;
  *(uint4*)dst = make_uint4(pk[0], pk[1], pk[2], pk[3]);
}

// ---------------------------------------------------------------- main
// LDS (bytes): SA 16K | SB 16K | SC 16K | SD 8K | RQ 36K (q^T f32 [256][36] -> ef f32 [32][256])
//              RH 32K (h1e bf16 SB=1024) | misc ~9.6K   => 136608 B, 1 block/CU, 16 waves.
__global__ __launch_bounds__(1024)
void moe_main(const float* __restrict__ node_features,
              const float* __restrict__ edge_features,
              const float* __restrict__ edge_raw,
              const int* __restrict__ neighbor_list,
              const float* __restrict__ neighbor_mask,
              const float* __restrict__ W_node_f32, const float* __restrict__ bn,
              const float* __restrict__ be, const float* __restrict__ bm,
              const float* __restrict__ bq, const float* __restrict__ bo,
              const float* __restrict__ ln_ffn_g, const float* __restrict__ ln_ffn_b,
              const float* __restrict__ W1n, const float* __restrict__ b1n,
              const float* __restrict__ W2n, const float* __restrict__ b2n,
              const float* __restrict__ b1e, const float* __restrict__ b2e,
              const unsigned short* __restrict__ nh16,
              const unsigned short* __restrict__ fb,
              const int* __restrict__ work_ne, const float* __restrict__ work_g,
              float* __restrict__ out_node, float* __restrict__ out_edge) {
  extern __shared__ char sm[];
  char* SAp = sm;              // 16K: sender -> msg -> ctx      (bf16 SB=512)
  char* SBp = sm + 16384;      // 16K: nodeh -> k -> eh2
  char* SCp = sm + 32768;      // 16K: eh -> v
  char* SDp = sm + 49152;      // 8K : edge_raw bf16 (SB=256)
  float* RQf = (float*)(sm + 57344);   // q^T [256][36] f32 -> ef [32][256] f32
  char* RHp = sm + 94208;      // 32K: h1e bf16 (SB=1024)
  float* MF = (float*)(sm + 126976);
  float* Mrecv = MF;           // 256 (later holds Mrv = recv@Wn2 + bn)
  float* Mrv4  = MF + 256;     // 1024
  float* Mnp   = MF + 1280;    // 256
  float* Mnh2  = MF + 1536;    // 256
  float* Mh1   = MF + 1792;    // 512
  float* Mred  = MF + 2304;    // 8
  float* Mmask = MF + 2312;    // 32
  float* Mmu   = MF + 2344;    // 32
  float* Mrstd = MF + 2376;    // 32

  const int t = threadIdx.x;
  const int pe = work_ne[blockIdx.x];
  const int n = pe >> 3, e = pe & 7;
  const float gate = work_g[blockIdx.x];

  const unsigned short* fbE   = fb + (size_t)e * EXP_STRIDE;
  const unsigned short* fbWn  = fbE + OFF_WN;
  const unsigned short* fbWm  = fbE + OFF_WM;
  const unsigned short* fbWe  = fbE + OFF_WE;
  const unsigned short* fbWq  = fbE + OFF_WQ;
  const unsigned short* fbWo  = fbE + OFF_WO;
  const unsigned short* fbW1e = fbE + OFF_W1E;
  const unsigned short* fbW2e = fbE + OFF_W2E;

  const float* Wn2  = W_node_f32 + (size_t)e * 131072;  // rows 256.. used
  const float* bnE  = bn + e * H_DIM;
  const float* beE  = be + e * H_DIM;
  const float* bmE  = bm + e * H_DIM;
  const float* bqE  = bq + e * 3 * H_DIM;
  const float* boE  = bo + e * H_DIM;
  const float* lfg  = ln_ffn_g + e * H_DIM;
  const float* lfb  = ln_ffn_b + e * H_DIM;
  const float* w1n  = W1n + (size_t)e * H_DIM * FFH;
  const float* c1n  = b1n + e * FFH;
  const float* w2n  = W2n + (size_t)e * FFH * H_DIM;
  const float* c2n  = b2n + e * H_DIM;
  const float* c1e  = b1e + e * FFH;
  const float* c2e  = b2e + e * H_DIM;

  const int w = t >> 6, l = t & 63;
  const int rt = w & 1, ctb = w >> 1;

  // ---- stage ----
  const unsigned short* nh_e = nh16 + (size_t)e * N_NODES * H_DIM;
  {
    int r = t >> 5, j = t & 31;
    int nbr = neighbor_list[n * K_NB + r];
    uint4 val = ((const uint4*)(nh_e + (size_t)nbr * H_DIM))[j];
    *(uint4*)(SAp + ((r * 512 + j * 16) ^ ((r & 7) << 4))) = val;
  }
  if (t < 256) Mrecv[t] = bf2f(nh_e[(size_t)n * H_DIM + t]);
  {
    int idx = t * 4, r = t >> 5, c = (t & 31) * 4;
    float4 v = *(const float4*)(edge_raw + ((size_t)n * K_NB + r) * DE_DIM + c);
    unsigned p0 = (unsigned)f2bf(v.x) | ((unsigned)f2bf(v.y) << 16);
    unsigned p1 = (unsigned)f2bf(v.z) | ((unsigned)f2bf(v.w) << 16);
    *(uint2*)(SDp + ((r * 256 + c * 2) ^ ((r & 7) << 4))) = make_uint2(p0, p1);
    (void)idx;
  }
  if (t < 32) Mmask[t] = neighbor_mask[n * K_NB + t];
  if (t < 256) Mnp[t] = 0.f;
  __syncthreads();

  // ---- recv rank-1 part: Mrv[c] = sum_i recv[i]*Wn[256+i][c] + bn[c] (fp32) ----
  {
    int c = t & 255, part = t >> 8;
    float s = 0.f;
    for (int i = 0; i < 64; ++i)
      s += Mrecv[part * 64 + i] * Wn2[(size_t)(256 + part * 64 + i) * 256 + c];
    Mrv4[part * 256 + c] = s;
  }
  __syncthreads();
  if (t < 256)
    Mrecv[t] = Mrv4[t] + Mrv4[256 + t] + Mrv4[512 + t] + Mrv4[768 + t] + bnE[t];
  __syncthreads();

  // ---- phase 1: nodeh = gelu(sender@Wn1 + Mrv) -> SB ----
  {
    f4v acc[2];
#pragma unroll
    for (int m = 0; m < 2; ++m) {
      float iv = Mrecv[(ctb + 8 * m) * 16 + (l & 15)];
      acc[m][0] = iv; acc[m][1] = iv; acc[m][2] = iv; acc[m][3] = iv;
    }
    kloop<2, 8>(acc, SAp, 512, rt, fbWn, 16, 0, ctb, l);
#pragma unroll
    for (int m = 0; m < 2; ++m) {
      int c = (ctb + 8 * m) * 16 + (l & 15);
#pragma unroll
      for (int ri = 0; ri < 4; ++ri)
        stb16(SBp, 512, rt * 16 + ((l >> 4) << 2) + ri, c, gelu_f(acc[m][ri]));
    }
  }
  // ---- phase 3: eh = gelu(edge_raw@We + be) -> SC ----
  {
    f4v acc[2];
#pragma unroll
    for (int m = 0; m < 2; ++m) {
      float iv = beE[(ctb + 8 * m) * 16 + (l & 15)];
      acc[m][0] = iv; acc[m][1] = iv; acc[m][2] = iv; acc[m][3] = iv;
    }
    kloop<2, 4>(acc, SDp, 256, rt, fbWe, 16, 0, ctb, l);
#pragma unroll
    for (int m = 0; m < 2; ++m) {
      int c = (ctb + 8 * m) * 16 + (l & 15);
#pragma unroll
      for (int ri = 0; ri < 4; ++ri)
        stb16(SCp, 512, rt * 16 + ((l >> 4) << 2) + ri, c, gelu_f(acc[m][ri]));
    }
  }
  __syncthreads();

  // ---- phase 2+4: msg = gelu([eh|nodeh]@Wm + bm) -> SA ----
  {
    f4v acc[2];
#pragma unroll
    for (int m = 0; m < 2; ++m) {
      float iv = bmE[(ctb + 8 * m) * 16 + (l & 15)];
      acc[m][0] = iv; acc[m][1] = iv; acc[m][2] = iv; acc[m][3] = iv;
    }
    kloop<2, 8>(acc, SCp, 512, rt, fbWm, 16, 0, ctb, l);   // eh   (Wm rows 0..255)
    kloop<2, 8>(acc, SBp, 512, rt, fbWm, 16, 8, ctb, l);   // nodeh(Wm rows 256..511)
#pragma unroll
    for (int m = 0; m < 2; ++m) {
      int c = (ctb + 8 * m) * 16 + (l & 15);
#pragma unroll
      for (int ri = 0; ri < 4; ++ri)
        stb16(SAp, 512, rt * 16 + ((l >> 4) << 2) + ri, c, gelu_f(acc[m][ri]));
    }
  }
  __syncthreads();

  // ---- phase 5: qkv = msg@Wq + bq; q^T f32->RQ, k->SB bf16, v->SC bf16 ----
  {
    f4v acc[6];
#pragma unroll
    for (int m = 0; m < 6; ++m) {
      float iv = bqE[(ctb + 8 * m) * 16 + (l & 15)];
      acc[m][0] = iv; acc[m][1] = iv; acc[m][2] = iv; acc[m][3] = iv;
    }
    kloop<6, 8>(acc, SAp, 512, rt, fbWq, 48, 0, ctb, l);
#pragma unroll
    for (int m = 0; m < 6; ++m) {
      int cg = (ctb + 8 * m) * 16 + (l & 15);
      int rbase = rt * 16 + ((l >> 4) << 2);
      if (cg < 256) {
        *(float4*)(RQf + cg * 36 + rbase) =
            make_float4(acc[m][0], acc[m][1], acc[m][2], acc[m][3]);
      } else if (cg < 512) {
#pragma unroll
        for (int ri = 0; ri < 4; ++ri) stb16(SBp, 512, rbase + ri, cg - 256, acc[m][ri]);
      } else {
#pragma unroll
        for (int ri = 0; ri < 4; ++ri) stb16(SCp, 512, rbase + ri, cg - 512, acc[m][ri]);
      }
    }
  }
  __syncthreads();

  // ---- phase 6: attention (t<256: h=t>>5, q=t&31); fp32 acc, bf16 k/v ----
  if (t < 256) {
    const int hh = (t >> 5) & 7, qq = t & 31;
    float s[32];
#pragma unroll
    for (int kk = 0; kk < 32; ++kk) s[kk] = 0.f;
#pragma unroll
    for (int d4 = 0; d4 < 8; ++d4) {
      int dbase = hh * 32 + d4 * 4;
      float q0 = RQf[(dbase + 0) * 36 + qq];
      float q1 = RQf[(dbase + 1) * 36 + qq];
      float q2 = RQf[(dbase + 2) * 36 + qq];
      float q3 = RQf[(dbase + 3) * 36 + qq];
#pragma unroll
      for (int kk = 0; kk < 32; ++kk) {
        uint2 kb = *(const uint2*)(SBp + ((kk * 512 + dbase * 2) ^ ((kk & 7) << 4)));
        s[kk] += q0 * bf2f(kb.x & 0xffff) + q1 * bf2f(kb.x >> 16) +
                 q2 * bf2f(kb.y & 0xffff) + q3 * bf2f(kb.y >> 16);
      }
    }
    const float scale = 0.17677669529663687f;
    float m = -3.4e38f;
#pragma unroll
    for (int kk = 0; kk < 32; ++kk) {
      float mv = (Mmask[kk] > 0.f) ? 0.f : -1e9f;
      s[kk] = s[kk] * scale + mv;
      m = fmaxf(m, s[kk]);
    }
    float sum = 0.f;
#pragma unroll
    for (int kk = 0; kk < 32; ++kk) { s[kk] = __expf(s[kk] - m); sum += s[kk]; }
    float inv = 1.f / sum;
#pragma unroll
    for (int kk = 0; kk < 32; ++kk) s[kk] *= inv;
#pragma unroll
    for (int d4 = 0; d4 < 8; ++d4) {
      int dbase = hh * 32 + d4 * 4;
      float x0 = 0.f, x1 = 0.f, x2 = 0.f, x3 = 0.f;
#pragma unroll
      for (int kk = 0; kk < 32; ++kk) {
        uint2 vb = *(const uint2*)(SCp + ((kk * 512 + dbase * 2) ^ ((kk & 7) << 4)));
        x0 += s[kk] * bf2f(vb.x & 0xffff); x1 += s[kk] * bf2f(vb.x >> 16);
        x2 += s[kk] * bf2f(vb.y & 0xffff); x3 += s[kk] * bf2f(vb.y >> 16);
      }
      unsigned p0 = (unsigned)f2bf(x0) | ((unsigned)f2bf(x1) << 16);
      unsigned p1 = (unsigned)f2bf(x2) | ((unsigned)f2bf(x3) << 16);
      *(uint2*)(SAp + ((qq * 512 + dbase * 2) ^ ((qq & 7) << 4))) = make_uint2(p0, p1);
    }
  }
  __syncthreads();

  // ---- phase 7: edge_out = ctx@Wo + bo; np partials; ef = eo + edge_features -> RQ ----
  {
    f4v acc[2];
#pragma unroll
    for (int m = 0; m < 2; ++m) {
      float iv = boE[(ctb + 8 * m) * 16 + (l & 15)];
      acc[m][0] = iv; acc[m][1] = iv; acc[m][2] = iv; acc[m][3] = iv;
    }
    kloop<2, 8>(acc, SAp, 512, rt, fbWo, 16, 0, ctb, l);
#pragma unroll
    for (int m = 0; m < 2; ++m) {
      int c = (ctb + 8 * m) * 16 + (l & 15);
      int rbase = rt * 16 + ((l >> 4) << 2);
      float np = 0.f;
#pragma unroll
      for (int ri = 0; ri < 4; ++ri) {
        int r = rbase + ri;
        float eo = acc[m][ri];
        np += eo * Mmask[r];
        RQf[r * 256 + c] = eo + edge_features[((size_t)n * K_NB + r) * H_DIM + c];
      }
      atomicAdd(&Mnp[c], np);
    }
  }
  __syncthreads();

  // ---- phase 9a: LN stats of ef; 8a: nfv + node-LN partials ----
  {
    int rr = t >> 5, j = t & 31;
    float s1 = 0.f, s2 = 0.f;
#pragma unroll
    for (int m2 = 0; m2 < 8; ++m2) {
      float xv = RQf[rr * 256 + j + 32 * m2];
      s1 += xv; s2 += xv * xv;
    }
    s1 += __shfl_xor(s1, 16, 32); s2 += __shfl_xor(s2, 16, 32);
    s1 += __shfl_xor(s1, 8, 32);  s2 += __shfl_xor(s2, 8, 32);
    s1 += __shfl_xor(s1, 4, 32);  s2 += __shfl_xor(s2, 4, 32);
    s1 += __shfl_xor(s1, 2, 32);  s2 += __shfl_xor(s2, 2, 32);
    s1 += __shfl_xor(s1, 1, 32);  s2 += __shfl_xor(s2, 1, 32);
    if (j == 0) {
      float mu2 = s1 * (1.f / 256.f);
      float v2 = s2 * (1.f / 256.f) - mu2 * mu2;
      Mmu[rr] = mu2; Mrstd[rr] = rsqrtf(v2 + 1e-5f);
    }
  }
  float cntv = 1e-5f;
#pragma unroll
  for (int kk = 0; kk < 32; ++kk) cntv += Mmask[kk];
  float nfv = 0.f;
  if (t < 256) {
    nfv = Mnp[t] / cntv + node_features[n * H_DIM + t];
    float sv = nfv, sq = nfv * nfv;
    for (int m = 32; m >= 1; m >>= 1) { sv += __shfl_xor(sv, m, 64); sq += __shfl_xor(sq, m, 64); }
    if ((t & 63) == 0) { Mred[t >> 6] = sv; Mred[4 + (t >> 6)] = sq; }
  }
  __syncthreads();

  // ---- 9c: node LN -> Mnh2 ; 9d: eh2 = LN(ef) -> SB bf16 ----
  if (t < 256) {
    float sum = Mred[0] + Mred[1] + Mred[2] + Mred[3];
    float ssum = Mred[4] + Mred[5] + Mred[6] + Mred[7];
    float mu = sum * (1.f / 256.f);
    float var = ssum * (1.f / 256.f) - mu * mu;
    float rstd = rsqrtf(var + 1e-5f);
    Mnh2[t] = (nfv - mu) * rstd * lfg[t] + lfb[t];
  }
  {
    int col = t & 255, rgp = t >> 8;
    float g2 = lfg[col], b2v = lfb[col];
#pragma unroll
    for (int r8 = 0; r8 < 8; ++r8) {
      int row = rgp * 8 + r8;
      float xv = (RQf[row * 256 + col] - Mmu[row]) * Mrstd[row] * g2 + b2v;
      stb16(SBp, 512, row, col, xv);
    }
  }
  __syncthreads();

  // ---- phase 10: h1e = gelu(eh2@w1e + c1e) -> RH (SB=1024); 8b: Mh1 ----
  {
    f4v acc[4];
#pragma unroll
    for (int m = 0; m < 4; ++m) {
      float iv = c1e[(ctb + 8 * m) * 16 + (l & 15)];
      acc[m][0] = iv; acc[m][1] = iv; acc[m][2] = iv; acc[m][3] = iv;
    }
    kloop<4, 8>(acc, SBp, 512, rt, fbW1e, 32, 0, ctb, l);
#pragma unroll
    for (int m = 0; m < 4; ++m) {
      int c = (ctb + 8 * m) * 16 + (l & 15);
#pragma unroll
      for (int ri = 0; ri < 4; ++ri)
        stb16(RHp, 1024, rt * 16 + ((l >> 4) << 2) + ri, c, gelu_f(acc[m][ri]));
    }
  }
  if (t < FFH) {
    float a = c1n[t];
    for (int i = 0; i < H_DIM; ++i) a += Mnh2[i] * w1n[(size_t)i * FFH + t];
    Mh1[t] = gelu_f(a);
  }
  __syncthreads();

  // ---- phase 11: out_e = ef + h1e@w2e + c2e ; 8c: out_node ----
  {
    f4v acc[2];
#pragma unroll
    for (int m = 0; m < 2; ++m) {
      float iv = c2e[(ctb + 8 * m) * 16 + (l & 15)];
      acc[m][0] = iv; acc[m][1] = iv; acc[m][2] = iv; acc[m][3] = iv;
    }
    kloop<2, 16>(acc, RHp, 1024, rt, fbW2e, 16, 0, ctb, l);
#pragma unroll
    for (int m = 0; m < 2; ++m) {
      int c = (ctb + 8 * m) * 16 + (l & 15);
      int rbase = rt * 16 + ((l >> 4) << 2);
#pragma unroll
      for (int ri = 0; ri < 4; ++ri) {
        int r = rbase + ri;
        float o = acc[m][ri] + RQf[r * 256 + c];
        atomicAdd(&out_edge[((size_t)n * K_NB + r) * H_DIM + c], gate * o);
      }
    }
  }
  if (t < 256) {
    float o = nfv + c2n[t];
    for (int i = 0; i < FFH; ++i) o += Mh1[i] * w2n[(size_t)i * H_DIM + t];
    atomicAdd(&out_node[n * H_DIM + t], gate * o);
  }
}

// ---------------------------------------------------------------- launch
extern "C" void kernel_launch(void* const* d_in, const int* in_sizes, int n_in,
                              void* d_out, int out_size, void* d_ws, size_t ws_size,
                              hipStream_t stream) {
  const float* node_features = (const float*)d_in[0];
  const float* edge_features = (const float*)d_in[1];
  const float* edge_raw      = (const float*)d_in[2];
  const int*   neighbor_list = (const int*)d_in[3];
  const float* neighbor_mask = (const float*)d_in[4];
  const float* w_gate        = (const float*)d_in[6];
  const float* W_edge = (const float*)d_in[7];
  const float* b_edge = (const float*)d_in[8];
  const float* W_node = (const float*)d_in[9];
  const float* b_node = (const float*)d_in[10];
  const float* W_msg  = (const float*)d_in[11];
  const float* b_msg  = (const float*)d_in[12];
  const float* W_qkv  = (const float*)d_in[13];
  const float* b_qkv  = (const float*)d_in[14];
  const float* W_out  = (const float*)d_in[15];
  const float* b_out  = (const float*)d_in[16];
  const float* ln_attn_g = (const float*)d_in[17];
  const float* ln_attn_b = (const float*)d_in[18];
  const float* ln_ffn_g  = (const float*)d_in[19];
  const float* ln_ffn_b  = (const float*)d_in[20];
  const float* W1n = (const float*)d_in[21];
  const float* b1n = (const float*)d_in[22];
  const float* W2n = (const float*)d_in[23];
  const float* b2n = (const float*)d_in[24];
  const float* W1e = (const float*)d_in[25];
  const float* b1e = (const float*)d_in[26];
  const float* W2e = (const float*)d_in[27];
  const float* b2e = (const float*)d_in[28];

  unsigned short* nh16 = (unsigned short*)d_ws;           // 2097152 bf16
  unsigned short* fbp  = nh16 + NH_ELEMS;                 // 6029312 bf16
  int*   sel_ne  = (int*)(fbp + (size_t)N_EXP * EXP_STRIDE);
  float* sel_g   = (float*)(sel_ne + 2048);
  int*   work_ne = (int*)(sel_g + 2048);
  float* work_g  = (float*)(work_ne + 2048);

  float* out_node = (float*)d_out;
  float* out_edge = out_node + N_NODES * H_DIM;

  hipMemsetAsync(d_out, 0, (size_t)out_size * sizeof(float), stream);

  gate_kernel<<<N_NODES, 64, 0, stream>>>(node_features, w_gate, sel_ne, sel_g);
  sort_kernel<<<1, 256, 0, stream>>>(sel_ne, sel_g, work_ne, work_g);
  nh_kernel<<<dim3(N_NODES, N_EXP), 256, 0, stream>>>(node_features, ln_attn_g, ln_attn_b, nh16);
  wconv<<<dim3(1472, N_EXP), 64, 0, stream>>>(W_node, W_msg, W_edge, W_qkv, W_out, W1e, W2e, fbp);

  size_t smem = 136640;
  hipFuncSetAttribute((const void*)moe_main, hipFuncAttributeMaxDynamicSharedMemorySize, (int)smem);
  moe_main<<<N_NODES * NTOPK, 1024, smem, stream>>>(
      node_features, edge_features, edge_raw, neighbor_list, neighbor_mask,
      W_node, b_node, b_edge, b_msg, b_qkv, b_out,
      ln_ffn_g, ln_ffn_b, W1n, b1n, W2n, b2n, b1e, b2e,
      nh16, fbp, work_ne, work_g, out_node, out_edge);
}